// Round 10
// baseline (421.837 us; speedup 1.0000x reference)
//
#include <hip/hip_runtime.h>
#include <hip/hip_bf16.h>
#include <cstdint>
#include <math.h>

// PathwayGraphEncoder: 3-layer GAT (+self-loops, scatter-softmax) -> mean pool
// -> VAE head with JAX partitionable-threefry eps.
// R20 = R19 + build||gemm1 fusion, R14 root cause fixed. R14 failed because
// 30.7KB static LDS -> 2 blocks per 64KB LDS pool -> 25% occupancy strangled
// the txn-bound build. Fix: gemm1 drops the 24KB B-stage (Wt1 = 128KB is
// L2-resident; bfr loads 16B/lane direct from global) -> only 6KB A-stage in
// LDS -> ~6 blocks/CU, build keeps its natural ~60% occupancy. wt_all runs
// as its own ~3us kernel first so Wt1 is ready (no race). Layers 2/3 gemms
// keep the proven Bs-staged form. agg4 (63us, 3.5TB/s combined gather
// service ~= R9's 3.7TB/s floor) and build (60us txn floor) are at their
// measured limits; this serial->parallel conversion is the last proven slack.

#define N_NODES 50000
#define N_EDGES 800000
#define NEG_SLOPE 0.2f
#define CAP 128
#define GB1 ((N_NODES+63)/64)    // gemm1 blocks in fused kernel

typedef __hip_bfloat16 bf16;
typedef short short8 __attribute__((ext_vector_type(8)));
typedef float floatx4 __attribute__((ext_vector_type(4)));
typedef float floatx2 __attribute__((ext_vector_type(2)));

__device__ __forceinline__ float bf2f(bf16 v){ return __bfloat162float(v); }
__device__ __forceinline__ float bflo(unsigned u){ union{unsigned u; float f;} c; c.u = u<<16; return c.f; }
__device__ __forceinline__ float bfhi(unsigned u){ union{unsigned u; float f;} c; c.u = u & 0xFFFF0000u; return c.f; }
__device__ __forceinline__ float leaky(float v){ return v>0.f ? v : NEG_SLOPE*v; }
__device__ __forceinline__ unsigned short f2bu(float f){
  union{ bf16 b; unsigned short u; } c; c.b = __float2bfloat16(f); return c.u;
}
__device__ __forceinline__ unsigned char f2fp8(float v){
  int p = __builtin_amdgcn_cvt_pk_fp8_f32(v, v, 0, false);
  return (unsigned char)(p & 0xff);
}
__device__ __forceinline__ void acc_fp8x4(float* acc, unsigned wrd, float wgt){
  floatx2 lo = __builtin_amdgcn_cvt_pk_f32_fp8((int)wrd, false);
  floatx2 hi = __builtin_amdgcn_cvt_pk_f32_fp8((int)wrd, true);
  acc[0] = fmaf(lo[0], wgt, acc[0]);
  acc[1] = fmaf(lo[1], wgt, acc[1]);
  acc[2] = fmaf(hi[0], wgt, acc[2]);
  acc[3] = fmaf(hi[1], wgt, acc[3]);
}

// ---------------- threefry2x32 (JAX-compatible) ----------------
__device__ __forceinline__ void tf_round(unsigned& x0, unsigned& x1, int r){
  x0 += x1; x1 = (x1<<r)|(x1>>(32-r)); x1 ^= x0;
}
__device__ __forceinline__ void threefry2x32(unsigned k0, unsigned k1, unsigned& x0, unsigned& x1){
  unsigned ks2 = k0 ^ k1 ^ 0x1BD11BDAu;
  x0 += k0; x1 += k1;
  tf_round(x0,x1,13); tf_round(x0,x1,15); tf_round(x0,x1,26); tf_round(x0,x1,6);
  x0 += k1; x1 += ks2 + 1u;
  tf_round(x0,x1,17); tf_round(x0,x1,29); tf_round(x0,x1,16); tf_round(x0,x1,24);
  x0 += ks2; x1 += k0 + 2u;
  tf_round(x0,x1,13); tf_round(x0,x1,15); tf_round(x0,x1,26); tf_round(x0,x1,6);
  x0 += k0; x1 += k1 + 3u;
  tf_round(x0,x1,17); tf_round(x0,x1,29); tf_round(x0,x1,16); tf_round(x0,x1,24);
  x0 += k1; x1 += ks2 + 4u;
  tf_round(x0,x1,13); tf_round(x0,x1,15); tf_round(x0,x1,26); tf_round(x0,x1,6);
  x0 += ks2; x1 += k0 + 5u;
}

// Giles single-precision erfinv (XLA ErfInv32 coefficients)
__device__ __forceinline__ float erfinv_approx(float x){
  float w = -log1pf(-x*x);
  float p;
  if (w < 5.0f){
    w = w - 2.5f;
    p = 2.81022636e-08f;
    p = fmaf(p,w,3.43273939e-07f);
    p = fmaf(p,w,-3.5233877e-06f);
    p = fmaf(p,w,-4.39150654e-06f);
    p = fmaf(p,w,0.00021858087f);
    p = fmaf(p,w,-0.00125372503f);
    p = fmaf(p,w,-0.00417768164f);
    p = fmaf(p,w,0.246640727f);
    p = fmaf(p,w,1.50140941f);
  } else {
    w = sqrtf(w) - 3.0f;
    p = -0.000200214257f;
    p = fmaf(p,w,0.000100950558f);
    p = fmaf(p,w,0.00134934322f);
    p = fmaf(p,w,-0.00367342844f);
    p = fmaf(p,w,0.00573950773f);
    p = fmaf(p,w,-0.0076224613f);
    p = fmaf(p,w,0.00943887047f);
    p = fmaf(p,w,1.00167406f);
    p = fmaf(p,w,2.83297682f);
  }
  return p*x;
}

// ------- W transposes (all 3 in one launch): Wt[n][k] bf16 from W[k][n] f32 -------
__global__ __launch_bounds__(256) void wt_all_kernel(
        const float* __restrict__ W1, const float* __restrict__ W2,
        const float* __restrict__ W3, short* __restrict__ Wt1,
        short* __restrict__ Wt2, short* __restrict__ Wt3){
  const float* W; short* Wt; int Nn;
  if (blockIdx.z == 0){ W = W1; Wt = Wt1; Nn = 256; }
  else if (blockIdx.z == 1){ W = W2; Wt = Wt2; Nn = 256; }
  else { W = W3; Wt = Wt3; Nn = 64; }
  const int n0 = blockIdx.x*32, k0 = blockIdx.y*32;
  if (n0 >= Nn) return;
  __shared__ float tile[32][33];
  const int tx = threadIdx.x & 31, ty = threadIdx.x >> 5;   // 32 x 8
  #pragma unroll
  for (int i=0;i<4;++i)
    tile[ty+8*i][tx] = W[(size_t)(k0+ty+8*i)*Nn + n0 + tx];
  __syncthreads();
  #pragma unroll
  for (int i=0;i<4;++i)
    Wt[(size_t)(n0+ty+8*i)*256 + k0 + tx] = (short)f2bu(tile[tx][ty+8*i]);
}

// ---- fused: gemm1 (blocks [0,GB1), 6KB LDS, B from global) || CSR build ----
// gemm1: M_BLK=64, OUT=256 fp8, input x f32. B-fragments load direct from
// Wt1 (L2-resident 128KB) -> no 24KB Bs stage -> LDS=6KB -> ~6 blocks/CU ->
// build path keeps its natural occupancy (the R14 fix).
// build: rank = atomicAdd(deg[dst]) IS the slot; deg[] INCLUDES self-loop.
__global__ __launch_bounds__(256) void fused_g1b_kernel(
        const float* __restrict__ x, const short* __restrict__ Wt1,
        unsigned char* __restrict__ hB8,
        const float* __restrict__ a1s, const float* __restrict__ a1d,
        float* __restrict__ als, float* __restrict__ ald,
        const int* __restrict__ ei, int* __restrict__ deg,
        unsigned short* __restrict__ csr){
  __shared__ short As[64*48];
  const int bx = (int)blockIdx.x;
  if (bx >= GB1){
    int idx = (bx - GB1)*256 + (int)threadIdx.x;
    if (idx < N_EDGES + N_NODES){
      int s_ = (idx < N_EDGES) ? ei[idx]          : idx - N_EDGES;
      int d_ = (idx < N_EDGES) ? ei[N_EDGES+idx]  : idx - N_EDGES;
      int r = atomicAdd(&deg[d_], 1);
      if (r < CAP) csr[(size_t)d_*CAP + r] = (unsigned short)s_;
    }
    return;
  }
  const int t = threadIdx.x;
  const int w = t>>6, lane = t&63;
  const int lm = lane&15, g = lane>>4;
  const int m0 = bx * 64;
  const int n0 = w*64;

  floatx4 acc[4][4] = {};

  for (int kk=0; kk<8; ++kk){
    const int k0 = kk*32;
    __syncthreads();
    for (int a = t; a < 64*4; a += 256){
      int r = a>>2, c = a&3;
      int gr = m0 + r;
      uint4 v = make_uint4(0u,0u,0u,0u);
      if (gr < N_NODES){
        const float* p = x + (size_t)gr*256 + k0 + c*8;
        float4 f0 = *(const float4*)p;
        float4 f1 = *(const float4*)(p+4);
        v.x = (unsigned)f2bu(f0.x) | ((unsigned)f2bu(f0.y)<<16);
        v.y = (unsigned)f2bu(f0.z) | ((unsigned)f2bu(f0.w)<<16);
        v.z = (unsigned)f2bu(f1.x) | ((unsigned)f2bu(f1.y)<<16);
        v.w = (unsigned)f2bu(f1.z) | ((unsigned)f2bu(f1.w)<<16);
      }
      *(uint4*)&As[r*48 + c*8] = v;
    }
    __syncthreads();
    short8 af[4], bfr[4];
    #pragma unroll
    for (int mt=0;mt<4;++mt)
      af[mt] = *(const short8*)&As[(mt*16 + lm)*48 + g*8];
    #pragma unroll
    for (int nt=0;nt<4;++nt)
      bfr[nt] = *(const short8*)(Wt1 + (size_t)(n0 + nt*16 + lm)*256 + k0 + g*8);
    #pragma unroll
    for (int mt=0;mt<4;++mt)
      #pragma unroll
      for (int nt=0;nt<4;++nt)
        acc[mt][nt] = __builtin_amdgcn_mfma_f32_16x16x32_bf16(af[mt], bfr[nt], acc[mt][nt], 0, 0, 0);
  }

  float asv[4], adv[4];
  #pragma unroll
  for (int nt=0;nt<4;++nt){
    asv[nt] = a1s[n0 + nt*16 + lm];
    adv[nt] = a1d[n0 + nt*16 + lm];
  }
  #pragma unroll
  for (int mt=0;mt<4;++mt){
    #pragma unroll
    for (int reg=0;reg<4;++reg){
      int gr = m0 + mt*16 + g*4 + reg;
      bool valid = gr < N_NODES;
      float ps = 0.f, pd = 0.f;
      #pragma unroll
      for (int nt=0;nt<4;++nt){
        float v = acc[mt][nt][reg];
        if (valid) hB8[(size_t)gr*256 + n0 + nt*16 + lm] = f2fp8(v);
        ps = fmaf(v, asv[nt], ps);
        pd = fmaf(v, adv[nt], pd);
      }
      #pragma unroll
      for (int o=1;o<16;o<<=1){ ps += __shfl_xor(ps,o); pd += __shfl_xor(pd,o); }
      if (lm==0 && valid){
        als[gr*4 + w] = ps;
        ald[gr*4 + w] = pd;
      }
    }
  }
}

// ---------------- MFMA GEMM + fused attention coefficients (layers 2/3) ----------------
// OUT=256: out is fp8 e4m3 [node][256]. OUT=64: out is fp8 e4m3 [node][64].
template<int OUT, bool INBF>
__global__ __launch_bounds__(256) void gemm_mfma_kernel(const void* __restrict__ inp,
        const short* __restrict__ Wt, void* __restrict__ outv,
        const float* __restrict__ a_s, const float* __restrict__ a_d,
        float* __restrict__ als, float* __restrict__ ald, int N){
  constexpr int M_BLK = (OUT==256) ? 64 : 256;
  constexpr int H = (OUT==256) ? 4 : 1;
  __shared__ short As[M_BLK*48];
  __shared__ short Bs[OUT*48];
  const int t = threadIdx.x;
  const int w = t>>6, lane = t&63;
  const int lm = lane&15, g = lane>>4;
  const int m0 = blockIdx.x * M_BLK;
  const int m_off = (OUT==256) ? 0 : w*64;
  const int n0    = (OUT==256) ? w*64 : 0;

  floatx4 acc[4][4] = {};

  for (int kk=0; kk<8; ++kk){
    const int k0 = kk*32;
    __syncthreads();
    for (int a = t; a < M_BLK*4; a += 256){
      int r = a>>2, c = a&3;
      int gr = m0 + r;
      uint4 v = make_uint4(0u,0u,0u,0u);
      if (gr < N){
        if constexpr (INBF){
          v = *(const uint4*)((const bf16*)inp + (size_t)gr*256 + k0 + c*8);
        } else {
          const float* p = (const float*)inp + (size_t)gr*256 + k0 + c*8;
          float4 f0 = *(const float4*)p;
          float4 f1 = *(const float4*)(p+4);
          v.x = (unsigned)f2bu(f0.x) | ((unsigned)f2bu(f0.y)<<16);
          v.y = (unsigned)f2bu(f0.z) | ((unsigned)f2bu(f0.w)<<16);
          v.z = (unsigned)f2bu(f1.x) | ((unsigned)f2bu(f1.y)<<16);
          v.w = (unsigned)f2bu(f1.z) | ((unsigned)f2bu(f1.w)<<16);
        }
      }
      *(uint4*)&As[r*48 + c*8] = v;
    }
    for (int a = t; a < OUT*4; a += 256){
      int r = a>>2, c = a&3;
      uint4 v = *(const uint4*)(Wt + (size_t)r*256 + k0 + c*8);
      *(uint4*)&Bs[r*48 + c*8] = v;
    }
    __syncthreads();
    short8 af[4], bfr[4];
    #pragma unroll
    for (int mt=0;mt<4;++mt)
      af[mt] = *(const short8*)&As[(m_off + mt*16 + lm)*48 + g*8];
    #pragma unroll
    for (int nt=0;nt<4;++nt)
      bfr[nt] = *(const short8*)&Bs[(n0 + nt*16 + lm)*48 + g*8];
    #pragma unroll
    for (int mt=0;mt<4;++mt)
      #pragma unroll
      for (int nt=0;nt<4;++nt)
        acc[mt][nt] = __builtin_amdgcn_mfma_f32_16x16x32_bf16(af[mt], bfr[nt], acc[mt][nt], 0, 0, 0);
  }

  float asv[4], adv[4];
  #pragma unroll
  for (int nt=0;nt<4;++nt){
    asv[nt] = a_s[n0 + nt*16 + lm];
    adv[nt] = a_d[n0 + nt*16 + lm];
  }
  const int head = (OUT==256) ? w : 0;
  #pragma unroll
  for (int mt=0;mt<4;++mt){
    #pragma unroll
    for (int reg=0;reg<4;++reg){
      int gr = m0 + m_off + mt*16 + g*4 + reg;
      bool valid = gr < N;
      float ps = 0.f, pd = 0.f;
      #pragma unroll
      for (int nt=0;nt<4;++nt){
        float v = acc[mt][nt][reg];
        if (valid){
          ((unsigned char*)outv)[(size_t)gr*OUT + n0 + nt*16 + lm] = f2fp8(v);
        }
        ps = fmaf(v, asv[nt], ps);
        pd = fmaf(v, adv[nt], pd);
      }
      #pragma unroll
      for (int o=1;o<16;o<<=1){ ps += __shfl_xor(ps,o); pd += __shfl_xor(pd,o); }
      if (lm==0 && valid){
        als[gr*H + head] = ps;
        ald[gr*H + head] = pd;
      }
    }
  }
}

// ------- scatter-softmax + aggregate, H=4, fp8 h (1 wave/node, 4 nodes/block) -------
// lane = parity r (lane>>4, 4 edges) x feature-16 f (lane&15); uint4 = 16 fp8
// => 4 rows per wave-instruction; combine via shfl_xor(16)+shfl_xor(32).
template<bool ELU>
__global__ __launch_bounds__(256) void aggregate4_kernel(const unsigned char* __restrict__ h8,
        const float* __restrict__ als, const float* __restrict__ ald,
        const int* __restrict__ deg, const unsigned short* __restrict__ csr,
        const float* __restrict__ bias, bf16* __restrict__ out){
  __shared__ int   s_src[4][64];
  __shared__ float s_w[4][64][4];
  const int wv_ = threadIdx.x >> 6;          // wave id (node within block)
  const int n = blockIdx.x*4 + wv_;
  if (n >= N_NODES) return;                  // whole wave exits together
  const int lane = threadIdx.x & 63;
  const int r = lane>>4;            // edge parity (0..3)
  const int f = lane&15;            // features f*16..f*16+15
  const int head = f>>2;
  const int p0 = n*CAP;
  const int cnt = min(deg[n], CAP); // includes self-loop
  const float4 aldn4 = *(const float4*)(ald + n*4);
  float ssum = 0.f;
  float acc[16] = {};
  for (int c=0; c<cnt; c+=64){
    int e = c + lane;
    int src = n; float4 w4 = make_float4(0.f,0.f,0.f,0.f);
    if (e < cnt){
      src = (int)csr[p0+e];
      float4 av = *(const float4*)(als + src*4);
      w4.x = expf(leaky(av.x + aldn4.x));
      w4.y = expf(leaky(av.y + aldn4.y));
      w4.z = expf(leaky(av.z + aldn4.z));
      w4.w = expf(leaky(av.w + aldn4.w));
    }
    s_src[wv_][lane] = src;            // pad: src=n (valid addr), w=0
    *(float4*)&s_w[wv_][lane][0] = w4;
    int ce = min(64, cnt - c);
    int cp = (ce+7)&~7;                // step 8: 2 uint4 loads in flight
    for (int i=0;i<cp;i+=8){
      int src0 = s_src[wv_][i+r], src1 = s_src[wv_][i+4+r];
      float w0 = s_w[wv_][i+r][head], w1 = s_w[wv_][i+4+r][head];
      uint4 h0 = *(const uint4*)(h8 + (size_t)src0*256 + f*16);
      uint4 h1 = *(const uint4*)(h8 + (size_t)src1*256 + f*16);
      ssum += w0 + w1;
      acc_fp8x4(acc+0,  h0.x, w0); acc_fp8x4(acc+4,  h0.y, w0);
      acc_fp8x4(acc+8,  h0.z, w0); acc_fp8x4(acc+12, h0.w, w0);
      acc_fp8x4(acc+0,  h1.x, w1); acc_fp8x4(acc+4,  h1.y, w1);
      acc_fp8x4(acc+8,  h1.z, w1); acc_fp8x4(acc+12, h1.w, w1);
    }
  }
  #pragma unroll
  for (int j=0;j<16;++j){
    acc[j] += __shfl_xor(acc[j], 16);
    acc[j] += __shfl_xor(acc[j], 32);
  }
  ssum += __shfl_xor(ssum, 16);
  ssum += __shfl_xor(ssum, 32);
  if (r==0){
    float inv = 1.f/(ssum + 1e-16f);
    #pragma unroll
    for (int half=0; half<2; ++half){
      float4 b0 = *(const float4*)(bias + f*16 + half*8);
      float4 b1 = *(const float4*)(bias + f*16 + half*8 + 4);
      float rv[8];
      rv[0]=acc[half*8+0]*inv+b0.x; rv[1]=acc[half*8+1]*inv+b0.y;
      rv[2]=acc[half*8+2]*inv+b0.z; rv[3]=acc[half*8+3]*inv+b0.w;
      rv[4]=acc[half*8+4]*inv+b1.x; rv[5]=acc[half*8+5]*inv+b1.y;
      rv[6]=acc[half*8+6]*inv+b1.z; rv[7]=acc[half*8+7]*inv+b1.w;
      union{ bf16 b[8]; uint4 u; } pk;
      #pragma unroll
      for (int j=0;j<8;++j){
        float v = rv[j];
        if (ELU) v = (v>0.f)?v:expm1f(v);
        pk.b[j] = __float2bfloat16(v);
      }
      *(uint4*)(out + (size_t)n*256 + f*16 + half*8) = pk.u;
    }
  }
}

// ------- scatter-softmax + aggregate, H=1, fp8 h3 (1 wave/node, 4 nodes/block) -------
__global__ __launch_bounds__(256) void aggregate1_kernel(const unsigned char* __restrict__ h8,
        const float* __restrict__ als, const float* __restrict__ ald,
        const int* __restrict__ deg, const unsigned short* __restrict__ csr,
        const float* __restrict__ bias, bf16* __restrict__ out){
  __shared__ int   s_src[4][64];
  __shared__ float s_w[4][64];
  const int wv_ = threadIdx.x >> 6;
  const int n = blockIdx.x*4 + wv_;
  if (n >= N_NODES) return;
  const int lane = threadIdx.x & 63;
  const int r = lane>>4;            // edge parity (0..3)
  const int f = lane&15;            // feature quad: features f*4..f*4+3
  const int p0 = n*CAP;
  const int cnt = min(deg[n], CAP); // includes self-loop
  const float aldn = ald[n];
  float ssum = 0.f;
  float acc[4] = {};
  for (int c=0; c<cnt; c+=64){
    int e = c + lane;
    int src = n; float wv = 0.f;
    if (e < cnt){
      src = (int)csr[p0+e];
      wv = expf(leaky(als[src] + aldn));
    }
    s_src[wv_][lane] = src; s_w[wv_][lane] = wv;
    int ce = min(64, cnt - c);
    int cp = (ce+7)&~7;              // step 8: 2 dword loads in flight
    for (int i=0;i<cp;i+=8){
      int src0 = s_src[wv_][i+r], src1 = s_src[wv_][i+4+r];
      float w0 = s_w[wv_][i+r],   w1 = s_w[wv_][i+4+r];
      unsigned h0 = *(const unsigned*)(h8 + (size_t)src0*64 + f*4);
      unsigned h1 = *(const unsigned*)(h8 + (size_t)src1*64 + f*4);
      ssum += w0 + w1;
      acc_fp8x4(acc, h0, w0);
      acc_fp8x4(acc, h1, w1);
    }
  }
  #pragma unroll
  for (int j=0;j<4;++j){
    acc[j] += __shfl_xor(acc[j], 16);
    acc[j] += __shfl_xor(acc[j], 32);
  }
  ssum += __shfl_xor(ssum, 16);
  ssum += __shfl_xor(ssum, 32);
  if (r==0){
    float inv = 1.f/(ssum + 1e-16f);
    union{ bf16 b[4]; uint2 u; } pk;
    #pragma unroll
    for (int j=0;j<4;++j) pk.b[j] = __float2bfloat16(acc[j]*inv + bias[f*4+j]);
    *(uint2*)(out + (size_t)n*64 + f*4) = pk.u;
  }
}

// ---------------- chunked pooling (batch sorted) ----------------
__global__ __launch_bounds__(64) void pool_kernel(const bf16* __restrict__ h3,
        const int* __restrict__ batch, float* __restrict__ psum, float* __restrict__ pcnt,
        int N, int chunk){
  int n0 = blockIdx.x*chunk;
  if (n0 >= N) return;
  int n1 = min(N, n0+chunk);
  int t = threadIdx.x;
  int gcur = batch[n0];
  float acc = 0.f, cnt = 0.f;
  for (int n=n0; n<n1; ++n){
    int g = batch[n];
    if (g != gcur){
      atomicAdd(&psum[gcur*64+t], acc);
      if (t==0) atomicAdd(&pcnt[gcur], cnt);
      acc = 0.f; cnt = 0.f; gcur = g;
    }
    acc += bf2f(h3[(size_t)n*64+t]);
    cnt += 1.f;
  }
  atomicAdd(&psum[gcur*64+t], acc);
  if (t==0) atomicAdd(&pcnt[gcur], cnt);
}

__global__ __launch_bounds__(64) void head_kernel(const float* __restrict__ psum,
        const float* __restrict__ pcnt,
        const float* __restrict__ Wmu, const float* __restrict__ bmu,
        const float* __restrict__ Wlv, const float* __restrict__ blv,
        float* __restrict__ out){
  int g = blockIdx.x, t = threadIdx.x;
  __shared__ float p[64];
  float cnt = fmaxf(pcnt[g], 1.0f);
  p[t] = psum[g*64+t] / cnt;
  __syncthreads();
  float mu = bmu[t], lv = blv[t];
  for (int k=0;k<64;++k){
    float pk = p[k];
    mu = fmaf(pk, Wmu[(size_t)k*64+t], mu);
    lv = fmaf(pk, Wlv[(size_t)k*64+t], lv);
  }
  int i = g*64 + t;
  unsigned x0 = 0u, x1 = (unsigned)i;
  threefry2x32(0u, 42u, x0, x1);
  unsigned bits = x0 ^ x1;
  float f = __uint_as_float((bits>>9) | 0x3F800000u) - 1.0f;   // [0,1)
  const float lo = __uint_as_float(0xBF7FFFFFu);               // -(1-2^-24)
  float u = fmaxf(lo, f*2.0f + lo);
  float eps = 1.41421356f * erfinv_approx(u);
  float z = mu + eps * expf(0.5f*lv);
  out[i]        = mu;
  out[4096 + i] = lv;
  out[8192 + i] = z;
}

// ---------------- launch ----------------
extern "C" void kernel_launch(void* const* d_in, const int* in_sizes, int n_in,
                              void* d_out, int out_size, void* d_ws, size_t ws_size,
                              hipStream_t stream){
  const float* x    = (const float*)d_in[0];
  const int*   ei   = (const int*)d_in[1];
  const int*   batch= (const int*)d_in[2];
  const float* W1   = (const float*)d_in[3];
  const float* a1s  = (const float*)d_in[4];
  const float* a1d  = (const float*)d_in[5];
  const float* b1   = (const float*)d_in[6];
  const float* W2   = (const float*)d_in[7];
  const float* a2s  = (const float*)d_in[8];
  const float* a2d  = (const float*)d_in[9];
  const float* b2   = (const float*)d_in[10];
  const float* W3   = (const float*)d_in[11];
  const float* a3s  = (const float*)d_in[12];
  const float* a3d  = (const float*)d_in[13];
  const float* b3   = (const float*)d_in[14];
  const float* Wmu  = (const float*)d_in[15];
  const float* bmu  = (const float*)d_in[16];
  const float* Wlv  = (const float*)d_in[17];
  const float* blv  = (const float*)d_in[18];
  float* out = (float*)d_out;

  const int N = N_NODES, E = N_EDGES;
  const int ET = E + N;

  char* ws = (char*)d_ws;
  size_t o = 0;
  auto alloc = [&](size_t bytes)->void*{
    void* p = ws + o; o += (bytes + 255) & ~(size_t)255; return p;
  };
  bf16*  hA      = (bf16*) alloc((size_t)N*256*2);       // 25.6 MB (agg out / gemm in)
  unsigned char* hB8 = (unsigned char*)alloc((size_t)N*256); // 12.8 MB fp8 gather payload
  unsigned char* h38 = (unsigned char*)alloc((size_t)N*64);  // 3.2 MB fp8 layer3 payload
  float* als     = (float*)alloc((size_t)N*4*4);
  float* ald     = (float*)alloc((size_t)N*4*4);
  // deg + psum/pcnt adjacent -> single memset covers both
  const size_t degBytes  = ((size_t)N*4 + 255) & ~(size_t)255;
  const size_t poolBytes = 64*64*4 + 64*4;
  int*   deg     = (int*)  alloc((size_t)N*4);
  float* psum    = (float*)alloc(poolBytes);
  float* pcnt    = psum + 64*64;
  unsigned short* csr16 = (unsigned short*)alloc((size_t)N*CAP*2); // 12.8 MB capped CSR
  short* Wt1     = (short*)alloc(256*256*2);
  short* Wt2     = (short*)alloc(256*256*2);
  short* Wt3     = (short*)alloc(64*256*2);
  (void)ws_size; (void)n_in; (void)in_sizes; (void)out_size;

  // zero deg + psum + pcnt in one shot (they are adjacent)
  hipMemsetAsync(deg, 0, degBytes + poolBytes, stream);

  // W transposes first (~3us) so Wt1 is ready for the fused kernel
  wt_all_kernel<<<dim3(8,8,3), 256, 0, stream>>>(W1, W2, W3, Wt1, Wt2, Wt3);

  // ---- layer 1 gemm (6KB LDS, B from global) || CSR build, one launch ----
  const int buildBlocks = (ET + 255)/256;
  fused_g1b_kernel<<<GB1 + buildBlocks, 256, 0, stream>>>(
      x, Wt1, hB8, a1s, a1d, als, ald, ei, deg, csr16);
  aggregate4_kernel<true><<<(N+3)/4, 256, 0, stream>>>(hB8, als, ald, deg, csr16, b1, hA);

  // ---- layer 2: hA(bf16) @ W2, H=4, ELU ----
  gemm_mfma_kernel<256,true><<<(N+63)/64, 256, 0, stream>>>(hA, Wt2, hB8, a2s, a2d, als, ald, N);
  aggregate4_kernel<true><<<(N+3)/4, 256, 0, stream>>>(hB8, als, ald, deg, csr16, b2, hA);

  // ---- layer 3: hA(bf16) @ W3, H=1, no ELU; h3 payload fp8 ----
  gemm_mfma_kernel<64,true><<<(N+255)/256, 256, 0, stream>>>(hA, Wt3, h38, a3s, a3d, als, ald, N);
  aggregate1_kernel<<<(N+3)/4, 256, 0, stream>>>(h38, als, ald, deg, csr16, b3, hA);

  // ---- pool + VAE head ----
  const int PBLK = 512;
  const int chunk = (N + PBLK - 1)/PBLK;
  pool_kernel<<<PBLK, 64, 0, stream>>>(hA, batch, psum, pcnt, N, chunk);
  head_kernel<<<64, 64, 0, stream>>>(psum, pcnt, Wmu, bmu, Wlv, blv, out);
}

// Round 11
// 417.758 us; speedup vs baseline: 1.0098x; 1.0098x over previous
//
#include <hip/hip_runtime.h>
#include <hip/hip_bf16.h>
#include <cstdint>
#include <math.h>

// PathwayGraphEncoder: 3-layer GAT (+self-loops, scatter-softmax) -> mean pool
// -> VAE head with JAX partitionable-threefry eps.
// R21 = exact revert to R19 (best measured: 418.0us). R20's third fusion
// attempt (6KB LDS, build-first) still collapsed to 25% occupancy/105us ->
// co-residency of the 850k-returning-atomic build with MFMA work poisons
// both (L2 queue saturation), independent of LDS. All remaining components
// at measured floors: build 60us (txn), agg4 2x63us (scattered-line ~3.5TB/s
// ~= 3.7TB/s ceiling), agg1 fp8'd, gemms/pool/head single-digit us.

#define N_NODES 50000
#define N_EDGES 800000
#define NEG_SLOPE 0.2f
#define CAP 128
#define WTB 192                  // wt-transpose blocks prefixed to build

typedef __hip_bfloat16 bf16;
typedef short short8 __attribute__((ext_vector_type(8)));
typedef float floatx4 __attribute__((ext_vector_type(4)));
typedef float floatx2 __attribute__((ext_vector_type(2)));

__device__ __forceinline__ float bf2f(bf16 v){ return __bfloat162float(v); }
__device__ __forceinline__ float bflo(unsigned u){ union{unsigned u; float f;} c; c.u = u<<16; return c.f; }
__device__ __forceinline__ float bfhi(unsigned u){ union{unsigned u; float f;} c; c.u = u & 0xFFFF0000u; return c.f; }
__device__ __forceinline__ float leaky(float v){ return v>0.f ? v : NEG_SLOPE*v; }
__device__ __forceinline__ unsigned short f2bu(float f){
  union{ bf16 b; unsigned short u; } c; c.b = __float2bfloat16(f); return c.u;
}
__device__ __forceinline__ unsigned char f2fp8(float v){
  int p = __builtin_amdgcn_cvt_pk_fp8_f32(v, v, 0, false);
  return (unsigned char)(p & 0xff);
}
__device__ __forceinline__ void acc_fp8x4(float* acc, unsigned wrd, float wgt){
  floatx2 lo = __builtin_amdgcn_cvt_pk_f32_fp8((int)wrd, false);
  floatx2 hi = __builtin_amdgcn_cvt_pk_f32_fp8((int)wrd, true);
  acc[0] = fmaf(lo[0], wgt, acc[0]);
  acc[1] = fmaf(lo[1], wgt, acc[1]);
  acc[2] = fmaf(hi[0], wgt, acc[2]);
  acc[3] = fmaf(hi[1], wgt, acc[3]);
}

// ---------------- threefry2x32 (JAX-compatible) ----------------
__device__ __forceinline__ void tf_round(unsigned& x0, unsigned& x1, int r){
  x0 += x1; x1 = (x1<<r)|(x1>>(32-r)); x1 ^= x0;
}
__device__ __forceinline__ void threefry2x32(unsigned k0, unsigned k1, unsigned& x0, unsigned& x1){
  unsigned ks2 = k0 ^ k1 ^ 0x1BD11BDAu;
  x0 += k0; x1 += k1;
  tf_round(x0,x1,13); tf_round(x0,x1,15); tf_round(x0,x1,26); tf_round(x0,x1,6);
  x0 += k1; x1 += ks2 + 1u;
  tf_round(x0,x1,17); tf_round(x0,x1,29); tf_round(x0,x1,16); tf_round(x0,x1,24);
  x0 += ks2; x1 += k0 + 2u;
  tf_round(x0,x1,13); tf_round(x0,x1,15); tf_round(x0,x1,26); tf_round(x0,x1,6);
  x0 += k0; x1 += k1 + 3u;
  tf_round(x0,x1,17); tf_round(x0,x1,29); tf_round(x0,x1,16); tf_round(x0,x1,24);
  x0 += k1; x1 += ks2 + 4u;
  tf_round(x0,x1,13); tf_round(x0,x1,15); tf_round(x0,x1,26); tf_round(x0,x1,6);
  x0 += ks2; x1 += k0 + 5u;
}

// Giles single-precision erfinv (XLA ErfInv32 coefficients)
__device__ __forceinline__ float erfinv_approx(float x){
  float w = -log1pf(-x*x);
  float p;
  if (w < 5.0f){
    w = w - 2.5f;
    p = 2.81022636e-08f;
    p = fmaf(p,w,3.43273939e-07f);
    p = fmaf(p,w,-3.5233877e-06f);
    p = fmaf(p,w,-4.39150654e-06f);
    p = fmaf(p,w,0.00021858087f);
    p = fmaf(p,w,-0.00125372503f);
    p = fmaf(p,w,-0.00417768164f);
    p = fmaf(p,w,0.246640727f);
    p = fmaf(p,w,1.50140941f);
  } else {
    w = sqrtf(w) - 3.0f;
    p = -0.000200214257f;
    p = fmaf(p,w,0.000100950558f);
    p = fmaf(p,w,0.00134934322f);
    p = fmaf(p,w,-0.00367342844f);
    p = fmaf(p,w,0.00573950773f);
    p = fmaf(p,w,-0.0076224613f);
    p = fmaf(p,w,0.00943887047f);
    p = fmaf(p,w,1.00167406f);
    p = fmaf(p,w,2.83297682f);
  }
  return p*x;
}

// ---- fused: W transposes (blocks [0,WTB)) + capped-CSR build (rest) ----
// wt: Wt[n][k] bf16 from W[k][n] f32, 32x32 tiles via 4.2KB LDS.
// build: rank = atomicAdd(deg[dst]) IS the slot; deg[] INCLUDES self-loop.
// 4.2KB static LDS does NOT cap the txn-bound build path (R18-verified:
// 58.5% occupancy, 59.7us = standalone build).
__global__ __launch_bounds__(256) void wt_build_kernel(
        const float* __restrict__ W1, const float* __restrict__ W2,
        const float* __restrict__ W3, short* __restrict__ Wt1,
        short* __restrict__ Wt2, short* __restrict__ Wt3,
        const int* __restrict__ ei, int* __restrict__ deg,
        unsigned short* __restrict__ csr){
  __shared__ float tile[32][33];
  const int bx = (int)blockIdx.x;
  if (bx < WTB){
    const int z = bx >> 6, rem = bx & 63;
    const int gx = rem & 7, gy = rem >> 3;
    const float* W; short* Wt; int Nn;
    if (z == 0){ W = W1; Wt = Wt1; Nn = 256; }
    else if (z == 1){ W = W2; Wt = Wt2; Nn = 256; }
    else { W = W3; Wt = Wt3; Nn = 64; }
    const int n0 = gx*32, k0 = gy*32;
    if (n0 >= Nn) return;
    const int tx = threadIdx.x & 31, ty = threadIdx.x >> 5;   // 32 x 8
    #pragma unroll
    for (int i=0;i<4;++i)
      tile[ty+8*i][tx] = W[(size_t)(k0+ty+8*i)*Nn + n0 + tx];
    __syncthreads();
    #pragma unroll
    for (int i=0;i<4;++i)
      Wt[(size_t)(n0+ty+8*i)*256 + k0 + tx] = (short)f2bu(tile[tx][ty+8*i]);
  } else {
    int idx = (bx - WTB)*256 + (int)threadIdx.x;
    if (idx < N_EDGES + N_NODES){
      int s_ = (idx < N_EDGES) ? ei[idx]          : idx - N_EDGES;
      int d_ = (idx < N_EDGES) ? ei[N_EDGES+idx]  : idx - N_EDGES;
      int r = atomicAdd(&deg[d_], 1);
      if (r < CAP) csr[(size_t)d_*CAP + r] = (unsigned short)s_;
    }
  }
}

// ---------------- MFMA GEMM + fused attention coefficients ----------------
// OUT=256: out is fp8 e4m3 [node][256]. OUT=64: out is fp8 e4m3 [node][64].
template<int OUT, bool INBF>
__global__ __launch_bounds__(256) void gemm_mfma_kernel(const void* __restrict__ inp,
        const short* __restrict__ Wt, void* __restrict__ outv,
        const float* __restrict__ a_s, const float* __restrict__ a_d,
        float* __restrict__ als, float* __restrict__ ald, int N){
  constexpr int M_BLK = (OUT==256) ? 64 : 256;
  constexpr int H = (OUT==256) ? 4 : 1;
  __shared__ short As[M_BLK*48];
  __shared__ short Bs[OUT*48];
  const int t = threadIdx.x;
  const int w = t>>6, lane = t&63;
  const int lm = lane&15, g = lane>>4;
  const int m0 = blockIdx.x * M_BLK;
  const int m_off = (OUT==256) ? 0 : w*64;
  const int n0    = (OUT==256) ? w*64 : 0;

  floatx4 acc[4][4] = {};

  for (int kk=0; kk<8; ++kk){
    const int k0 = kk*32;
    __syncthreads();
    for (int a = t; a < M_BLK*4; a += 256){
      int r = a>>2, c = a&3;
      int gr = m0 + r;
      uint4 v = make_uint4(0u,0u,0u,0u);
      if (gr < N){
        if constexpr (INBF){
          v = *(const uint4*)((const bf16*)inp + (size_t)gr*256 + k0 + c*8);
        } else {
          const float* p = (const float*)inp + (size_t)gr*256 + k0 + c*8;
          float4 f0 = *(const float4*)p;
          float4 f1 = *(const float4*)(p+4);
          v.x = (unsigned)f2bu(f0.x) | ((unsigned)f2bu(f0.y)<<16);
          v.y = (unsigned)f2bu(f0.z) | ((unsigned)f2bu(f0.w)<<16);
          v.z = (unsigned)f2bu(f1.x) | ((unsigned)f2bu(f1.y)<<16);
          v.w = (unsigned)f2bu(f1.z) | ((unsigned)f2bu(f1.w)<<16);
        }
      }
      *(uint4*)&As[r*48 + c*8] = v;
    }
    for (int a = t; a < OUT*4; a += 256){
      int r = a>>2, c = a&3;
      uint4 v = *(const uint4*)(Wt + (size_t)r*256 + k0 + c*8);
      *(uint4*)&Bs[r*48 + c*8] = v;
    }
    __syncthreads();
    short8 af[4], bfr[4];
    #pragma unroll
    for (int mt=0;mt<4;++mt)
      af[mt] = *(const short8*)&As[(m_off + mt*16 + lm)*48 + g*8];
    #pragma unroll
    for (int nt=0;nt<4;++nt)
      bfr[nt] = *(const short8*)&Bs[(n0 + nt*16 + lm)*48 + g*8];
    #pragma unroll
    for (int mt=0;mt<4;++mt)
      #pragma unroll
      for (int nt=0;nt<4;++nt)
        acc[mt][nt] = __builtin_amdgcn_mfma_f32_16x16x32_bf16(af[mt], bfr[nt], acc[mt][nt], 0, 0, 0);
  }

  float asv[4], adv[4];
  #pragma unroll
  for (int nt=0;nt<4;++nt){
    asv[nt] = a_s[n0 + nt*16 + lm];
    adv[nt] = a_d[n0 + nt*16 + lm];
  }
  const int head = (OUT==256) ? w : 0;
  #pragma unroll
  for (int mt=0;mt<4;++mt){
    #pragma unroll
    for (int reg=0;reg<4;++reg){
      int gr = m0 + m_off + mt*16 + g*4 + reg;
      bool valid = gr < N;
      float ps = 0.f, pd = 0.f;
      #pragma unroll
      for (int nt=0;nt<4;++nt){
        float v = acc[mt][nt][reg];
        if (valid){
          ((unsigned char*)outv)[(size_t)gr*OUT + n0 + nt*16 + lm] = f2fp8(v);
        }
        ps = fmaf(v, asv[nt], ps);
        pd = fmaf(v, adv[nt], pd);
      }
      #pragma unroll
      for (int o=1;o<16;o<<=1){ ps += __shfl_xor(ps,o); pd += __shfl_xor(pd,o); }
      if (lm==0 && valid){
        als[gr*H + head] = ps;
        ald[gr*H + head] = pd;
      }
    }
  }
}

// ------- scatter-softmax + aggregate, H=4, fp8 h (1 wave/node, 4 nodes/block) -------
// lane = parity r (lane>>4, 4 edges) x feature-16 f (lane&15); uint4 = 16 fp8
// => 4 rows per wave-instruction; combine via shfl_xor(16)+shfl_xor(32).
template<bool ELU>
__global__ __launch_bounds__(256) void aggregate4_kernel(const unsigned char* __restrict__ h8,
        const float* __restrict__ als, const float* __restrict__ ald,
        const int* __restrict__ deg, const unsigned short* __restrict__ csr,
        const float* __restrict__ bias, bf16* __restrict__ out){
  __shared__ int   s_src[4][64];
  __shared__ float s_w[4][64][4];
  const int wv_ = threadIdx.x >> 6;          // wave id (node within block)
  const int n = blockIdx.x*4 + wv_;
  if (n >= N_NODES) return;                  // whole wave exits together
  const int lane = threadIdx.x & 63;
  const int r = lane>>4;            // edge parity (0..3)
  const int f = lane&15;            // features f*16..f*16+15
  const int head = f>>2;
  const int p0 = n*CAP;
  const int cnt = min(deg[n], CAP); // includes self-loop
  const float4 aldn4 = *(const float4*)(ald + n*4);
  float ssum = 0.f;
  float acc[16] = {};
  for (int c=0; c<cnt; c+=64){
    int e = c + lane;
    int src = n; float4 w4 = make_float4(0.f,0.f,0.f,0.f);
    if (e < cnt){
      src = (int)csr[p0+e];
      float4 av = *(const float4*)(als + src*4);
      w4.x = expf(leaky(av.x + aldn4.x));
      w4.y = expf(leaky(av.y + aldn4.y));
      w4.z = expf(leaky(av.z + aldn4.z));
      w4.w = expf(leaky(av.w + aldn4.w));
    }
    s_src[wv_][lane] = src;            // pad: src=n (valid addr), w=0
    *(float4*)&s_w[wv_][lane][0] = w4;
    int ce = min(64, cnt - c);
    int cp = (ce+7)&~7;                // step 8: 2 uint4 loads in flight
    for (int i=0;i<cp;i+=8){
      int src0 = s_src[wv_][i+r], src1 = s_src[wv_][i+4+r];
      float w0 = s_w[wv_][i+r][head], w1 = s_w[wv_][i+4+r][head];
      uint4 h0 = *(const uint4*)(h8 + (size_t)src0*256 + f*16);
      uint4 h1 = *(const uint4*)(h8 + (size_t)src1*256 + f*16);
      ssum += w0 + w1;
      acc_fp8x4(acc+0,  h0.x, w0); acc_fp8x4(acc+4,  h0.y, w0);
      acc_fp8x4(acc+8,  h0.z, w0); acc_fp8x4(acc+12, h0.w, w0);
      acc_fp8x4(acc+0,  h1.x, w1); acc_fp8x4(acc+4,  h1.y, w1);
      acc_fp8x4(acc+8,  h1.z, w1); acc_fp8x4(acc+12, h1.w, w1);
    }
  }
  #pragma unroll
  for (int j=0;j<16;++j){
    acc[j] += __shfl_xor(acc[j], 16);
    acc[j] += __shfl_xor(acc[j], 32);
  }
  ssum += __shfl_xor(ssum, 16);
  ssum += __shfl_xor(ssum, 32);
  if (r==0){
    float inv = 1.f/(ssum + 1e-16f);
    #pragma unroll
    for (int half=0; half<2; ++half){
      float4 b0 = *(const float4*)(bias + f*16 + half*8);
      float4 b1 = *(const float4*)(bias + f*16 + half*8 + 4);
      float rv[8];
      rv[0]=acc[half*8+0]*inv+b0.x; rv[1]=acc[half*8+1]*inv+b0.y;
      rv[2]=acc[half*8+2]*inv+b0.z; rv[3]=acc[half*8+3]*inv+b0.w;
      rv[4]=acc[half*8+4]*inv+b1.x; rv[5]=acc[half*8+5]*inv+b1.y;
      rv[6]=acc[half*8+6]*inv+b1.z; rv[7]=acc[half*8+7]*inv+b1.w;
      union{ bf16 b[8]; uint4 u; } pk;
      #pragma unroll
      for (int j=0;j<8;++j){
        float v = rv[j];
        if (ELU) v = (v>0.f)?v:expm1f(v);
        pk.b[j] = __float2bfloat16(v);
      }
      *(uint4*)(out + (size_t)n*256 + f*16 + half*8) = pk.u;
    }
  }
}

// ------- scatter-softmax + aggregate, H=1, fp8 h3 (1 wave/node, 4 nodes/block) -------
__global__ __launch_bounds__(256) void aggregate1_kernel(const unsigned char* __restrict__ h8,
        const float* __restrict__ als, const float* __restrict__ ald,
        const int* __restrict__ deg, const unsigned short* __restrict__ csr,
        const float* __restrict__ bias, bf16* __restrict__ out){
  __shared__ int   s_src[4][64];
  __shared__ float s_w[4][64];
  const int wv_ = threadIdx.x >> 6;
  const int n = blockIdx.x*4 + wv_;
  if (n >= N_NODES) return;
  const int lane = threadIdx.x & 63;
  const int r = lane>>4;            // edge parity (0..3)
  const int f = lane&15;            // feature quad: features f*4..f*4+3
  const int p0 = n*CAP;
  const int cnt = min(deg[n], CAP); // includes self-loop
  const float aldn = ald[n];
  float ssum = 0.f;
  float acc[4] = {};
  for (int c=0; c<cnt; c+=64){
    int e = c + lane;
    int src = n; float wv = 0.f;
    if (e < cnt){
      src = (int)csr[p0+e];
      wv = expf(leaky(als[src] + aldn));
    }
    s_src[wv_][lane] = src; s_w[wv_][lane] = wv;
    int ce = min(64, cnt - c);
    int cp = (ce+7)&~7;              // step 8: 2 dword loads in flight
    for (int i=0;i<cp;i+=8){
      int src0 = s_src[wv_][i+r], src1 = s_src[wv_][i+4+r];
      float w0 = s_w[wv_][i+r],   w1 = s_w[wv_][i+4+r];
      unsigned h0 = *(const unsigned*)(h8 + (size_t)src0*64 + f*4);
      unsigned h1 = *(const unsigned*)(h8 + (size_t)src1*64 + f*4);
      ssum += w0 + w1;
      acc_fp8x4(acc, h0, w0);
      acc_fp8x4(acc, h1, w1);
    }
  }
  #pragma unroll
  for (int j=0;j<4;++j){
    acc[j] += __shfl_xor(acc[j], 16);
    acc[j] += __shfl_xor(acc[j], 32);
  }
  ssum += __shfl_xor(ssum, 16);
  ssum += __shfl_xor(ssum, 32);
  if (r==0){
    float inv = 1.f/(ssum + 1e-16f);
    union{ bf16 b[4]; uint2 u; } pk;
    #pragma unroll
    for (int j=0;j<4;++j) pk.b[j] = __float2bfloat16(acc[j]*inv + bias[f*4+j]);
    *(uint2*)(out + (size_t)n*64 + f*4) = pk.u;
  }
}

// ---------------- chunked pooling (batch sorted) ----------------
__global__ __launch_bounds__(64) void pool_kernel(const bf16* __restrict__ h3,
        const int* __restrict__ batch, float* __restrict__ psum, float* __restrict__ pcnt,
        int N, int chunk){
  int n0 = blockIdx.x*chunk;
  if (n0 >= N) return;
  int n1 = min(N, n0+chunk);
  int t = threadIdx.x;
  int gcur = batch[n0];
  float acc = 0.f, cnt = 0.f;
  for (int n=n0; n<n1; ++n){
    int g = batch[n];
    if (g != gcur){
      atomicAdd(&psum[gcur*64+t], acc);
      if (t==0) atomicAdd(&pcnt[gcur], cnt);
      acc = 0.f; cnt = 0.f; gcur = g;
    }
    acc += bf2f(h3[(size_t)n*64+t]);
    cnt += 1.f;
  }
  atomicAdd(&psum[gcur*64+t], acc);
  if (t==0) atomicAdd(&pcnt[gcur], cnt);
}

__global__ __launch_bounds__(64) void head_kernel(const float* __restrict__ psum,
        const float* __restrict__ pcnt,
        const float* __restrict__ Wmu, const float* __restrict__ bmu,
        const float* __restrict__ Wlv, const float* __restrict__ blv,
        float* __restrict__ out){
  int g = blockIdx.x, t = threadIdx.x;
  __shared__ float p[64];
  float cnt = fmaxf(pcnt[g], 1.0f);
  p[t] = psum[g*64+t] / cnt;
  __syncthreads();
  float mu = bmu[t], lv = blv[t];
  for (int k=0;k<64;++k){
    float pk = p[k];
    mu = fmaf(pk, Wmu[(size_t)k*64+t], mu);
    lv = fmaf(pk, Wlv[(size_t)k*64+t], lv);
  }
  int i = g*64 + t;
  unsigned x0 = 0u, x1 = (unsigned)i;
  threefry2x32(0u, 42u, x0, x1);
  unsigned bits = x0 ^ x1;
  float f = __uint_as_float((bits>>9) | 0x3F800000u) - 1.0f;   // [0,1)
  const float lo = __uint_as_float(0xBF7FFFFFu);               // -(1-2^-24)
  float u = fmaxf(lo, f*2.0f + lo);
  float eps = 1.41421356f * erfinv_approx(u);
  float z = mu + eps * expf(0.5f*lv);
  out[i]        = mu;
  out[4096 + i] = lv;
  out[8192 + i] = z;
}

// ---------------- launch ----------------
extern "C" void kernel_launch(void* const* d_in, const int* in_sizes, int n_in,
                              void* d_out, int out_size, void* d_ws, size_t ws_size,
                              hipStream_t stream){
  const float* x    = (const float*)d_in[0];
  const int*   ei   = (const int*)d_in[1];
  const int*   batch= (const int*)d_in[2];
  const float* W1   = (const float*)d_in[3];
  const float* a1s  = (const float*)d_in[4];
  const float* a1d  = (const float*)d_in[5];
  const float* b1   = (const float*)d_in[6];
  const float* W2   = (const float*)d_in[7];
  const float* a2s  = (const float*)d_in[8];
  const float* a2d  = (const float*)d_in[9];
  const float* b2   = (const float*)d_in[10];
  const float* W3   = (const float*)d_in[11];
  const float* a3s  = (const float*)d_in[12];
  const float* a3d  = (const float*)d_in[13];
  const float* b3   = (const float*)d_in[14];
  const float* Wmu  = (const float*)d_in[15];
  const float* bmu  = (const float*)d_in[16];
  const float* Wlv  = (const float*)d_in[17];
  const float* blv  = (const float*)d_in[18];
  float* out = (float*)d_out;

  const int N = N_NODES, E = N_EDGES;
  const int ET = E + N;

  char* ws = (char*)d_ws;
  size_t o = 0;
  auto alloc = [&](size_t bytes)->void*{
    void* p = ws + o; o += (bytes + 255) & ~(size_t)255; return p;
  };
  bf16*  hA      = (bf16*) alloc((size_t)N*256*2);       // 25.6 MB (agg out / gemm in)
  unsigned char* hB8 = (unsigned char*)alloc((size_t)N*256); // 12.8 MB fp8 gather payload
  unsigned char* h38 = (unsigned char*)alloc((size_t)N*64);  // 3.2 MB fp8 layer3 payload
  float* als     = (float*)alloc((size_t)N*4*4);
  float* ald     = (float*)alloc((size_t)N*4*4);
  // deg + psum/pcnt adjacent -> single memset covers both
  const size_t degBytes  = ((size_t)N*4 + 255) & ~(size_t)255;
  const size_t poolBytes = 64*64*4 + 64*4;
  int*   deg     = (int*)  alloc((size_t)N*4);
  float* psum    = (float*)alloc(poolBytes);
  float* pcnt    = psum + 64*64;
  unsigned short* csr16 = (unsigned short*)alloc((size_t)N*CAP*2); // 12.8 MB capped CSR
  short* Wt1     = (short*)alloc(256*256*2);
  short* Wt2     = (short*)alloc(256*256*2);
  short* Wt3     = (short*)alloc(64*256*2);
  (void)ws_size; (void)n_in; (void)in_sizes; (void)out_size;

  // zero deg + psum + pcnt in one shot (they are adjacent)
  hipMemsetAsync(deg, 0, degBytes + poolBytes, stream);

  // W transposes (192-block prefix) + single-pass capped CSR build, one launch
  const int buildBlocks = (ET + 255)/256;
  wt_build_kernel<<<WTB + buildBlocks, 256, 0, stream>>>(
      W1, W2, W3, Wt1, Wt2, Wt3, ei, deg, csr16);

  // ---- layer 1: x(f32) @ W1, H=4, ELU ----
  gemm_mfma_kernel<256,false><<<(N+63)/64, 256, 0, stream>>>(x, Wt1, hB8, a1s, a1d, als, ald, N);
  aggregate4_kernel<true><<<(N+3)/4, 256, 0, stream>>>(hB8, als, ald, deg, csr16, b1, hA);

  // ---- layer 2: hA(bf16) @ W2, H=4, ELU ----
  gemm_mfma_kernel<256,true><<<(N+63)/64, 256, 0, stream>>>(hA, Wt2, hB8, a2s, a2d, als, ald, N);
  aggregate4_kernel<true><<<(N+3)/4, 256, 0, stream>>>(hB8, als, ald, deg, csr16, b2, hA);

  // ---- layer 3: hA(bf16) @ W3, H=1, no ELU; h3 payload fp8 ----
  gemm_mfma_kernel<64,true><<<(N+255)/256, 256, 0, stream>>>(hA, Wt3, h38, a3s, a3d, als, ald, N);
  aggregate1_kernel<<<(N+3)/4, 256, 0, stream>>>(h38, als, ald, deg, csr16, b3, hA);

  // ---- pool + VAE head ----
  const int PBLK = 512;
  const int chunk = (N + PBLK - 1)/PBLK;
  pool_kernel<<<PBLK, 64, 0, stream>>>(hA, batch, psum, pcnt, N, chunk);
  head_kernel<<<64, 64, 0, stream>>>(psum, pcnt, Wmu, bmu, Wlv, blv, out);
}